// Round 1
// baseline (1969.662 us; speedup 1.0000x reference)
//
#include <hip/hip_runtime.h>

// Problem constants (also derived from in_sizes at launch for safety)
static constexpr int FIN = 128;
static constexpr int HD  = 64;
static constexpr int CD  = 40;

// ---------------------------------------------------------------------------
// Dense: out[n][o] = (relu_out?)( bias[o] + sum_k in[n][k] * W[o][k] )
// One lane per node. Weight/bias indices are wave-uniform -> scalar loads
// through the constant cache; inputs are float4 vector loads.
// ---------------------------------------------------------------------------
template<int K, int O>
__global__ __launch_bounds__(64)
void lin_kernel(const float* __restrict__ in, const float* __restrict__ W,
                const float* __restrict__ bias, float* __restrict__ out, int n)
{
    int node = blockIdx.x * 64 + threadIdx.x;
    if (node >= n) return;
    float acc[O];
#pragma unroll
    for (int o = 0; o < O; ++o) acc[o] = bias[o];
    const float* row = in + (size_t)node * K;
#pragma unroll 2
    for (int k = 0; k < K; k += 4) {
        float4 v = *reinterpret_cast<const float4*>(row + k);
#pragma unroll
        for (int o = 0; o < O; ++o) {
            const float* wr = W + o * K + k;
            acc[o] = fmaf(v.x, wr[0], acc[o]);
            acc[o] = fmaf(v.y, wr[1], acc[o]);
            acc[o] = fmaf(v.z, wr[2], acc[o]);
            acc[o] = fmaf(v.w, wr[3], acc[o]);
        }
    }
    float* orow = out + (size_t)node * O;
#pragma unroll
    for (int o = 0; o < O; o += 4) {
        float4 r = make_float4(acc[o], acc[o + 1], acc[o + 2], acc[o + 3]);
        *reinterpret_cast<float4*>(orow + o) = r;
    }
}

// ---------------------------------------------------------------------------
// Fused conv tail: t = relu(agg); u = relu(W1 t + b1); out = W2 u + b2
// (optionally relu'd). One lane per node, weights via scalar loads.
// ---------------------------------------------------------------------------
template<int D, bool FINAL_RELU>
__global__ __launch_bounds__(64)
void post_kernel(const float* __restrict__ agg,
                 const float* __restrict__ W1, const float* __restrict__ b1,
                 const float* __restrict__ W2, const float* __restrict__ b2,
                 float* __restrict__ out, int n)
{
    int node = blockIdx.x * 64 + threadIdx.x;
    if (node >= n) return;
    float t[D];
    const float* row = agg + (size_t)node * D;
#pragma unroll
    for (int k = 0; k < D; k += 4) {
        float4 v = *reinterpret_cast<const float4*>(row + k);
        t[k]     = fmaxf(v.x, 0.f);
        t[k + 1] = fmaxf(v.y, 0.f);
        t[k + 2] = fmaxf(v.z, 0.f);
        t[k + 3] = fmaxf(v.w, 0.f);
    }
    float u[D];
#pragma unroll 2
    for (int o = 0; o < D; ++o) {
        float a = b1[o];
        const float* wr = W1 + o * D;
#pragma unroll
        for (int k = 0; k < D; ++k) a = fmaf(t[k], wr[k], a);
        u[o] = fmaxf(a, 0.f);
    }
    float* orow = out + (size_t)node * D;
#pragma unroll 2
    for (int o = 0; o < D; ++o) {
        float a = b2[o];
        const float* wr = W2 + o * D;
#pragma unroll
        for (int k = 0; k < D; ++k) a = fmaf(u[k], wr[k], a);
        if (FINAL_RELU) a = fmaxf(a, 0.f);
        orow[o] = a;
    }
}

// ---------------------------------------------------------------------------
// agg = h  (self-loop term), float4 grid-stride copy
// ---------------------------------------------------------------------------
__global__ __launch_bounds__(256)
void copy_kernel(const float4* __restrict__ in, float4* __restrict__ out, int n4)
{
    int stride = gridDim.x * blockDim.x;
    for (int i = blockIdx.x * blockDim.x + threadIdx.x; i < n4; i += stride)
        out[i] = in[i];
}

// ---------------------------------------------------------------------------
// Scatter-add: agg[dst] += h[src].  16 lanes/edge (D=64), float4 gather +
// 4 scalar fp32 atomics.
// ---------------------------------------------------------------------------
__global__ __launch_bounds__(256)
void scatter64_kernel(const int* __restrict__ src, const int* __restrict__ dst,
                      const float* __restrict__ h, float* __restrict__ agg, int e_count)
{
    long tid = (long)blockIdx.x * 256 + threadIdx.x;
    int e = (int)(tid >> 4);
    if (e >= e_count) return;
    int c = ((int)tid & 15) * 4;
    int s = src[e], d = dst[e];
    float4 v = *reinterpret_cast<const float4*>(h + (size_t)s * HD + c);
    float* a = agg + (size_t)d * HD + c;
    atomicAdd(a + 0, v.x);
    atomicAdd(a + 1, v.y);
    atomicAdd(a + 2, v.z);
    atomicAdd(a + 3, v.w);
}

// 10 lanes/edge (D=40)
__global__ __launch_bounds__(256)
void scatter40_kernel(const int* __restrict__ src, const int* __restrict__ dst,
                      const float* __restrict__ h, float* __restrict__ agg, int e_count)
{
    long tid = (long)blockIdx.x * 256 + threadIdx.x;
    int e = (int)(tid / 10);
    if (e >= e_count) return;
    int c = (int)(tid - (long)e * 10) * 4;
    int s = src[e], d = dst[e];
    float4 v = *reinterpret_cast<const float4*>(h + (size_t)s * CD + c);
    float* a = agg + (size_t)d * CD + c;
    atomicAdd(a + 0, v.x);
    atomicAdd(a + 1, v.y);
    atomicAdd(a + 2, v.z);
    atomicAdd(a + 3, v.w);
}

extern "C" void kernel_launch(void* const* d_in, const int* in_sizes, int n_in,
                              void* d_out, int out_size, void* d_ws, size_t ws_size,
                              hipStream_t stream)
{
    const float* x      = (const float*)d_in[0];
    const int*   ei     = (const int*)d_in[1];
    const float* w1_lin = (const float*)d_in[2];
    const float* b1_lin = (const float*)d_in[3];
    const float* w1_o1  = (const float*)d_in[4];
    const float* b1_o1  = (const float*)d_in[5];
    const float* w1_o2  = (const float*)d_in[6];
    const float* b1_o2  = (const float*)d_in[7];
    const float* w2_lin = (const float*)d_in[8];
    const float* b2_lin = (const float*)d_in[9];
    const float* w2_o1  = (const float*)d_in[10];
    const float* b2_o1  = (const float*)d_in[11];
    const float* w2_o2  = (const float*)d_in[12];
    const float* b2_o2  = (const float*)d_in[13];

    const int n = in_sizes[0] / FIN;   // 100000
    const int e = in_sizes[1] / 2;     // 1000000
    const int* src = ei;
    const int* dst = ei + e;

    // Workspace layout (reused across phases):
    //   ws0: n*HD floats   (h1, then hmid, then agg2)
    //   ws1: n*HD floats   (agg1, then h2)
    float* ws0 = (float*)d_ws;
    float* ws1 = ws0 + (size_t)n * HD;

    float* h1   = ws0;
    float* agg1 = ws1;
    float* hmid = ws0;   // overwrites h1 (only agg1 needed by then)
    float* h2   = ws1;   // overwrites agg1 (consumed by post1)
    float* agg2 = ws0;   // overwrites hmid (consumed by lin2)
    float* outp = (float*)d_out;

    const int ngrid = (n + 63) / 64;

    // conv1: h1 = x @ w1_lin.T + b1_lin
    lin_kernel<FIN, HD><<<ngrid, 64, 0, stream>>>(x, w1_lin, b1_lin, h1, n);
    // agg1 = h1 (self-loop)
    copy_kernel<<<2048, 256, 0, stream>>>((const float4*)h1, (float4*)agg1, n * HD / 4);
    // agg1 += scatter(h1[src] -> dst)
    {
        long threads = (long)e * 16;
        int blocks = (int)((threads + 255) / 256);
        scatter64_kernel<<<blocks, 256, 0, stream>>>(src, dst, h1, agg1, e);
    }
    // hmid = relu( relu(relu(agg1) @ o1 + b) @ o2 + b )
    post_kernel<HD, true><<<ngrid, 64, 0, stream>>>(agg1, w1_o1, b1_o1, w1_o2, b1_o2, hmid, n);

    // conv2: h2 = hmid @ w2_lin.T + b2_lin
    lin_kernel<HD, CD><<<ngrid, 64, 0, stream>>>(hmid, w2_lin, b2_lin, h2, n);
    // agg2 = h2
    copy_kernel<<<2048, 256, 0, stream>>>((const float4*)h2, (float4*)agg2, n * CD / 4);
    // agg2 += scatter(h2[src] -> dst)
    {
        long threads = (long)e * 10;
        int blocks = (int)((threads + 255) / 256);
        scatter40_kernel<<<blocks, 256, 0, stream>>>(src, dst, h2, agg2, e);
    }
    // out = relu(relu(agg2) @ o1 + b) @ o2 + b   (no final relu)
    post_kernel<CD, false><<<ngrid, 64, 0, stream>>>(agg2, w2_o1, b2_o1, w2_o2, b2_o2, outp, n);
}

// Round 2
// 744.786 us; speedup vs baseline: 2.6446x; 2.6446x over previous
//
#include <hip/hip_runtime.h>

static constexpr int FIN = 128;
static constexpr int HD  = 64;
static constexpr int CD  = 40;

// ---------------------------------------------------------------------------
// Dense: out[n][o] = bias[o] + sum_k in[n][k] * W[o][k].  One lane per node;
// weight indices wave-uniform -> scalar loads; inputs float4.
// ---------------------------------------------------------------------------
template<int K, int O>
__global__ __launch_bounds__(256)
void lin_kernel(const float* __restrict__ in, const float* __restrict__ W,
                const float* __restrict__ bias, float* __restrict__ out, int n)
{
    int node = blockIdx.x * 256 + threadIdx.x;
    if (node >= n) return;
    float acc[O];
#pragma unroll
    for (int o = 0; o < O; ++o) acc[o] = bias[o];
    const float* row = in + (size_t)node * K;
#pragma unroll 2
    for (int k = 0; k < K; k += 4) {
        float4 v = *reinterpret_cast<const float4*>(row + k);
#pragma unroll
        for (int o = 0; o < O; ++o) {
            const float* wr = W + o * K + k;
            acc[o] = fmaf(v.x, wr[0], acc[o]);
            acc[o] = fmaf(v.y, wr[1], acc[o]);
            acc[o] = fmaf(v.z, wr[2], acc[o]);
            acc[o] = fmaf(v.w, wr[3], acc[o]);
        }
    }
    float* orow = out + (size_t)node * O;
#pragma unroll
    for (int o = 0; o < O; o += 4)
        *reinterpret_cast<float4*>(orow + o) =
            make_float4(acc[o], acc[o + 1], acc[o + 2], acc[o + 3]);
}

// ---------------------------------------------------------------------------
// Fused conv tail: t = relu(agg); u = relu(W1 t + b1); out = W2 u + b2 (+relu)
// ---------------------------------------------------------------------------
template<int D, bool FINAL_RELU>
__global__ __launch_bounds__(256)
void post_kernel(const float* __restrict__ agg,
                 const float* __restrict__ W1, const float* __restrict__ b1,
                 const float* __restrict__ W2, const float* __restrict__ b2,
                 float* __restrict__ out, int n)
{
    int node = blockIdx.x * 256 + threadIdx.x;
    if (node >= n) return;
    float t[D];
    const float* row = agg + (size_t)node * D;
#pragma unroll
    for (int k = 0; k < D; k += 4) {
        float4 v = *reinterpret_cast<const float4*>(row + k);
        t[k] = fmaxf(v.x, 0.f); t[k+1] = fmaxf(v.y, 0.f);
        t[k+2] = fmaxf(v.z, 0.f); t[k+3] = fmaxf(v.w, 0.f);
    }
    float u[D];
#pragma unroll 2
    for (int o = 0; o < D; ++o) {
        float a = b1[o];
        const float* wr = W1 + o * D;
#pragma unroll
        for (int k = 0; k < D; ++k) a = fmaf(t[k], wr[k], a);
        u[o] = fmaxf(a, 0.f);
    }
    float* orow = out + (size_t)node * D;
#pragma unroll 2
    for (int o = 0; o < D; ++o) {
        float a = b2[o];
        const float* wr = W2 + o * D;
#pragma unroll
        for (int k = 0; k < D; ++k) a = fmaf(u[k], wr[k], a);
        if (FINAL_RELU) a = fmaxf(a, 0.f);
        orow[o] = a;
    }
}

// ---------------------------------------------------------------------------
// CSR build.  deg -> (chunk sums -> scan chunks -> scan within) -> rowptr
// (start offsets), then fill mutates rowptr to end offsets while writing eidx.
// Gather uses [rowptr[d]-deg[d], rowptr[d]).
// ---------------------------------------------------------------------------
__global__ __launch_bounds__(256)
void hist_kernel(const int* __restrict__ dst, int* __restrict__ deg, int e)
{
    int i = blockIdx.x * 256 + threadIdx.x;
    if (i < e) atomicAdd(&deg[dst[i]], 1);
}

// 1024 elems per block, 256 threads
__global__ __launch_bounds__(256)
void chunksum_kernel(const int* __restrict__ deg, int* __restrict__ chunkSum, int n)
{
    __shared__ int s[256];
    int t = threadIdx.x;
    int base = blockIdx.x * 1024 + t * 4;
    int v = 0;
#pragma unroll
    for (int i = 0; i < 4; ++i) if (base + i < n) v += deg[base + i];
    s[t] = v; __syncthreads();
    for (int off = 128; off > 0; off >>= 1) {
        if (t < off) s[t] += s[t + off];
        __syncthreads();
    }
    if (t == 0) chunkSum[blockIdx.x] = s[0];
}

// single block, up to 128 chunks -> exclusive scan in place
__global__ __launch_bounds__(128)
void scanchunks_kernel(int* __restrict__ chunkSum, int nchunks)
{
    __shared__ int s[128];
    int t = threadIdx.x;
    int v = (t < nchunks) ? chunkSum[t] : 0;
    s[t] = v; __syncthreads();
    for (int off = 1; off < 128; off <<= 1) {
        int a = (t >= off) ? s[t - off] : 0;
        __syncthreads();
        s[t] += a;
        __syncthreads();
    }
    if (t < nchunks) chunkSum[t] = s[t] - v;   // exclusive
}

__global__ __launch_bounds__(256)
void scanwithin_kernel(const int* __restrict__ deg, const int* __restrict__ chunkOff,
                       int* __restrict__ rowptr, int n)
{
    __shared__ int s[256];
    int t = threadIdx.x;
    int base = blockIdx.x * 1024 + t * 4;
    int v[4]; int sum = 0;
#pragma unroll
    for (int i = 0; i < 4; ++i) { v[i] = (base + i < n) ? deg[base + i] : 0; sum += v[i]; }
    s[t] = sum; __syncthreads();
    for (int off = 1; off < 256; off <<= 1) {
        int a = (t >= off) ? s[t - off] : 0;
        __syncthreads();
        s[t] += a;
        __syncthreads();
    }
    int p = s[t] - sum + chunkOff[blockIdx.x];   // exclusive across whole array
#pragma unroll
    for (int i = 0; i < 4; ++i) {
        if (base + i < n) rowptr[base + i] = p;
        p += v[i];
    }
}

__global__ __launch_bounds__(256)
void fill_kernel(const int* __restrict__ src, const int* __restrict__ dst,
                 int* __restrict__ rowptr, int* __restrict__ eidx, int e)
{
    int i = blockIdx.x * 256 + threadIdx.x;
    if (i >= e) return;
    int pos = atomicAdd(&rowptr[dst[i]], 1);
    eidx[pos] = src[i];
}

// ---------------------------------------------------------------------------
// Gather: agg[d][c] = h[d][c] + sum_{e: dst=d} h[src_e][c].
// One wave per node, lane = channel.  Edge ids batch-loaded + shfl-broadcast.
// ---------------------------------------------------------------------------
template<int D>
__global__ __launch_bounds__(256)
void gather_kernel(const int* __restrict__ rowptr_end, const int* __restrict__ deg,
                   const int* __restrict__ eidx, const float* __restrict__ h,
                   float* __restrict__ agg, int n)
{
    int wave = threadIdx.x >> 6;
    int lane = threadIdx.x & 63;
    int node = blockIdx.x * 4 + wave;
    if (node >= n) return;
    bool act = (lane < D);
    float acc = act ? h[(size_t)node * D + lane] : 0.f;
    int end = rowptr_end[node];
    int start = end - deg[node];
    for (int base = start; base < end; base += 64) {
        int m = min(64, end - base);
        int sv = (lane < m) ? eidx[base + lane] : 0;
        for (int j = 0; j < m; ++j) {
            int s = __shfl(sv, j, 64);
            if (act) acc += h[(size_t)s * D + lane];
        }
    }
    if (act) agg[(size_t)node * D + lane] = acc;
}

extern "C" void kernel_launch(void* const* d_in, const int* in_sizes, int n_in,
                              void* d_out, int out_size, void* d_ws, size_t ws_size,
                              hipStream_t stream)
{
    const float* x      = (const float*)d_in[0];
    const int*   ei     = (const int*)d_in[1];
    const float* w1_lin = (const float*)d_in[2];
    const float* b1_lin = (const float*)d_in[3];
    const float* w1_o1  = (const float*)d_in[4];
    const float* b1_o1  = (const float*)d_in[5];
    const float* w1_o2  = (const float*)d_in[6];
    const float* b1_o2  = (const float*)d_in[7];
    const float* w2_lin = (const float*)d_in[8];
    const float* b2_lin = (const float*)d_in[9];
    const float* w2_o1  = (const float*)d_in[10];
    const float* b2_o1  = (const float*)d_in[11];
    const float* w2_o2  = (const float*)d_in[12];
    const float* b2_o2  = (const float*)d_in[13];

    const int n = in_sizes[0] / FIN;   // 100000
    const int e = in_sizes[1] / 2;     // 1000000
    const int* src = ei;
    const int* dst = ei + e;

    // Float scratch in d_ws (same 51.2 MB footprint as the passing round-1):
    float* ws0 = (float*)d_ws;
    float* ws1 = ws0 + (size_t)n * HD;
    float* h1   = ws0;
    float* agg1 = ws1;
    float* hmid = ws0;   // overwrites h1 (h1 dead after gather64)
    float* h2   = ws1;   // overwrites agg1 (dead after post1)
    float* agg2 = ws0;   // overwrites hmid (dead after lin2)
    float* outp = (float*)d_out;

    // CSR arrays live in d_out (16 MB; free until the final post kernel).
    // eidx(e) + deg(n) + rowptr(n) + chunkSum(128) = ~4.8 MB.
    int* eidx     = (int*)d_out;
    int* deg      = eidx + e;
    int* rowptr   = deg + n;
    int* chunkSum = rowptr + n;

    const int nchunks = (n + 1023) / 1024;        // 98 (must be <= 128)
    const int egrid   = (e + 255) / 256;
    const int ngrid   = (n + 255) / 256;
    const int ggrid   = (n + 3) / 4;

    // ---- CSR build (once; reused by both layers) ----
    hipMemsetAsync(deg, 0, (size_t)n * sizeof(int), stream);
    hist_kernel<<<egrid, 256, 0, stream>>>(dst, deg, e);
    chunksum_kernel<<<nchunks, 256, 0, stream>>>(deg, chunkSum, n);
    scanchunks_kernel<<<1, 128, 0, stream>>>(chunkSum, nchunks);
    scanwithin_kernel<<<nchunks, 256, 0, stream>>>(deg, chunkSum, rowptr, n);
    fill_kernel<<<egrid, 256, 0, stream>>>(src, dst, rowptr, eidx, e);
    // now rowptr[d] = end offset; start = rowptr[d] - deg[d]

    // ---- conv1 ----
    lin_kernel<FIN, HD><<<ngrid, 256, 0, stream>>>(x, w1_lin, b1_lin, h1, n);
    gather_kernel<HD><<<ggrid, 256, 0, stream>>>(rowptr, deg, eidx, h1, agg1, n);
    post_kernel<HD, true><<<ngrid, 256, 0, stream>>>(agg1, w1_o1, b1_o1, w1_o2, b1_o2, hmid, n);

    // ---- conv2 ----
    lin_kernel<HD, CD><<<ngrid, 256, 0, stream>>>(hmid, w2_lin, b2_lin, h2, n);
    gather_kernel<CD><<<ggrid, 256, 0, stream>>>(rowptr, deg, eidx, h2, agg2, n);
    post_kernel<CD, false><<<ngrid, 256, 0, stream>>>(agg2, w2_o1, b2_o1, w2_o2, b2_o2, outp, n);
}

// Round 3
// 743.982 us; speedup vs baseline: 2.6475x; 1.0011x over previous
//
#include <hip/hip_runtime.h>

static constexpr int FIN = 128;
static constexpr int HD  = 64;
static constexpr int CD  = 40;

// ---------------------------------------------------------------------------
// Dense: out[n][o] = bias[o] + sum_k in[n][k] * W[o][k].  One lane per node;
// weight indices wave-uniform -> scalar loads; inputs float4.
// __launch_bounds__(256,3): VGPR cap ~168 — acc[64]+temps ~90 fits, NO SPILL.
// ---------------------------------------------------------------------------
template<int K, int O>
__global__ __launch_bounds__(256, 3)
void lin_kernel(const float* __restrict__ in, const float* __restrict__ W,
                const float* __restrict__ bias, float* __restrict__ out, int n)
{
    int node = blockIdx.x * 256 + threadIdx.x;
    if (node >= n) return;
    float acc[O];
#pragma unroll
    for (int o = 0; o < O; ++o) acc[o] = bias[o];
    const float* row = in + (size_t)node * K;
#pragma unroll 2
    for (int k = 0; k < K; k += 4) {
        float4 v = *reinterpret_cast<const float4*>(row + k);
#pragma unroll
        for (int o = 0; o < O; ++o) {
            const float* wr = W + o * K + k;
            acc[o] = fmaf(v.x, wr[0], acc[o]);
            acc[o] = fmaf(v.y, wr[1], acc[o]);
            acc[o] = fmaf(v.z, wr[2], acc[o]);
            acc[o] = fmaf(v.w, wr[3], acc[o]);
        }
    }
    float* orow = out + (size_t)node * O;
#pragma unroll
    for (int o = 0; o < O; o += 4)
        *reinterpret_cast<float4*>(orow + o) =
            make_float4(acc[o], acc[o + 1], acc[o + 2], acc[o + 3]);
}

// ---------------------------------------------------------------------------
// Fused conv1-tail + conv2-lin:
//   t = relu(agg); u = relu(W1 t + b1); w = relu(W2 u + b2); out = W3 w + b3
// Peak live regs ~130 (u[64]+t[64]) -> __launch_bounds__(256,2): cap ~256.
// ---------------------------------------------------------------------------
template<int D, int O>
__global__ __launch_bounds__(256, 2)
void postlin_kernel(const float* __restrict__ agg,
                    const float* __restrict__ W1, const float* __restrict__ b1,
                    const float* __restrict__ W2, const float* __restrict__ b2,
                    const float* __restrict__ W3, const float* __restrict__ b3,
                    float* __restrict__ out, int n)
{
    int node = blockIdx.x * 256 + threadIdx.x;
    if (node >= n) return;
    float t[D];
    const float* row = agg + (size_t)node * D;
#pragma unroll
    for (int k = 0; k < D; k += 4) {
        float4 v = *reinterpret_cast<const float4*>(row + k);
        t[k] = fmaxf(v.x, 0.f); t[k+1] = fmaxf(v.y, 0.f);
        t[k+2] = fmaxf(v.z, 0.f); t[k+3] = fmaxf(v.w, 0.f);
    }
    float u[D];
#pragma unroll 2
    for (int o = 0; o < D; ++o) {
        float a = b1[o];
        const float* wr = W1 + o * D;
#pragma unroll
        for (int k = 0; k < D; ++k) a = fmaf(t[k], wr[k], a);
        u[o] = fmaxf(a, 0.f);
    }
#pragma unroll 2
    for (int o = 0; o < D; ++o) {       // t = relu(W2 u + b2)  (hmid, incl. outer relu)
        float a = b2[o];
        const float* wr = W2 + o * D;
#pragma unroll
        for (int k = 0; k < D; ++k) a = fmaf(u[k], wr[k], a);
        t[o] = fmaxf(a, 0.f);
    }
    float* orow = out + (size_t)node * O;
#pragma unroll 2
    for (int o = 0; o < O; ++o) {       // out = W3 t + b3  (conv2 lin)
        float a = b3[o];
        const float* wr = W3 + o * D;
#pragma unroll
        for (int k = 0; k < D; ++k) a = fmaf(t[k], wr[k], a);
        orow[o] = a;
    }
}

// ---------------------------------------------------------------------------
// Conv tail: t = relu(agg); u = relu(W1 t + b1); out = W2 u + b2 (+opt relu)
// ---------------------------------------------------------------------------
template<int D, bool FINAL_RELU>
__global__ __launch_bounds__(256, 3)
void post_kernel(const float* __restrict__ agg,
                 const float* __restrict__ W1, const float* __restrict__ b1,
                 const float* __restrict__ W2, const float* __restrict__ b2,
                 float* __restrict__ out, int n)
{
    int node = blockIdx.x * 256 + threadIdx.x;
    if (node >= n) return;
    float t[D];
    const float* row = agg + (size_t)node * D;
#pragma unroll
    for (int k = 0; k < D; k += 4) {
        float4 v = *reinterpret_cast<const float4*>(row + k);
        t[k] = fmaxf(v.x, 0.f); t[k+1] = fmaxf(v.y, 0.f);
        t[k+2] = fmaxf(v.z, 0.f); t[k+3] = fmaxf(v.w, 0.f);
    }
    float u[D];
#pragma unroll 2
    for (int o = 0; o < D; ++o) {
        float a = b1[o];
        const float* wr = W1 + o * D;
#pragma unroll
        for (int k = 0; k < D; ++k) a = fmaf(t[k], wr[k], a);
        u[o] = fmaxf(a, 0.f);
    }
    float* orow = out + (size_t)node * D;
#pragma unroll 2
    for (int o = 0; o < D; ++o) {
        float a = b2[o];
        const float* wr = W2 + o * D;
#pragma unroll
        for (int k = 0; k < D; ++k) a = fmaf(u[k], wr[k], a);
        if (FINAL_RELU) a = fmaxf(a, 0.f);
        orow[o] = a;
    }
}

// ---------------------------------------------------------------------------
// CSR build.
// ---------------------------------------------------------------------------
__global__ __launch_bounds__(256)
void hist_kernel(const int* __restrict__ dst, int* __restrict__ deg, int e)
{
    int i = blockIdx.x * 256 + threadIdx.x;
    if (i < e) atomicAdd(&deg[dst[i]], 1);
}

__global__ __launch_bounds__(256)
void chunksum_kernel(const int* __restrict__ deg, int* __restrict__ chunkSum, int n)
{
    __shared__ int s[256];
    int t = threadIdx.x;
    int base = blockIdx.x * 1024 + t * 4;
    int v = 0;
#pragma unroll
    for (int i = 0; i < 4; ++i) if (base + i < n) v += deg[base + i];
    s[t] = v; __syncthreads();
    for (int off = 128; off > 0; off >>= 1) {
        if (t < off) s[t] += s[t + off];
        __syncthreads();
    }
    if (t == 0) chunkSum[blockIdx.x] = s[0];
}

__global__ __launch_bounds__(128)
void scanchunks_kernel(int* __restrict__ chunkSum, int nchunks)
{
    __shared__ int s[128];
    int t = threadIdx.x;
    int v = (t < nchunks) ? chunkSum[t] : 0;
    s[t] = v; __syncthreads();
    for (int off = 1; off < 128; off <<= 1) {
        int a = (t >= off) ? s[t - off] : 0;
        __syncthreads();
        s[t] += a;
        __syncthreads();
    }
    if (t < nchunks) chunkSum[t] = s[t] - v;   // exclusive
}

__global__ __launch_bounds__(256)
void scanwithin_kernel(const int* __restrict__ deg, const int* __restrict__ chunkOff,
                       int* __restrict__ rowptr, int n)
{
    __shared__ int s[256];
    int t = threadIdx.x;
    int base = blockIdx.x * 1024 + t * 4;
    int v[4]; int sum = 0;
#pragma unroll
    for (int i = 0; i < 4; ++i) { v[i] = (base + i < n) ? deg[base + i] : 0; sum += v[i]; }
    s[t] = sum; __syncthreads();
    for (int off = 1; off < 256; off <<= 1) {
        int a = (t >= off) ? s[t - off] : 0;
        __syncthreads();
        s[t] += a;
        __syncthreads();
    }
    int p = s[t] - sum + chunkOff[blockIdx.x];
#pragma unroll
    for (int i = 0; i < 4; ++i) {
        if (base + i < n) rowptr[base + i] = p;
        p += v[i];
    }
}

__global__ __launch_bounds__(256)
void fill_kernel(const int* __restrict__ src, const int* __restrict__ dst,
                 int* __restrict__ rowptr, int* __restrict__ eidx, int e)
{
    int i = blockIdx.x * 256 + threadIdx.x;
    if (i >= e) return;
    int pos = atomicAdd(&rowptr[dst[i]], 1);
    eidx[pos] = src[i];
}

// ---------------------------------------------------------------------------
// Gather: agg[d][c] = h[d][c] + sum_{e: dst=d} h[src_e][c].
// One wave per node, lane = channel.
// ---------------------------------------------------------------------------
template<int D>
__global__ __launch_bounds__(256)
void gather_kernel(const int* __restrict__ rowptr_end, const int* __restrict__ deg,
                   const int* __restrict__ eidx, const float* __restrict__ h,
                   float* __restrict__ agg, int n)
{
    int wave = threadIdx.x >> 6;
    int lane = threadIdx.x & 63;
    int node = blockIdx.x * 4 + wave;
    if (node >= n) return;
    bool act = (lane < D);
    float acc = act ? h[(size_t)node * D + lane] : 0.f;
    int end = rowptr_end[node];
    int start = end - deg[node];
    for (int base = start; base < end; base += 64) {
        int m = min(64, end - base);
        int sv = (lane < m) ? eidx[base + lane] : 0;
        for (int j = 0; j < m; ++j) {
            int s = __shfl(sv, j, 64);
            if (act) acc += h[(size_t)s * D + lane];
        }
    }
    if (act) agg[(size_t)node * D + lane] = acc;
}

extern "C" void kernel_launch(void* const* d_in, const int* in_sizes, int n_in,
                              void* d_out, int out_size, void* d_ws, size_t ws_size,
                              hipStream_t stream)
{
    const float* x      = (const float*)d_in[0];
    const int*   ei     = (const int*)d_in[1];
    const float* w1_lin = (const float*)d_in[2];
    const float* b1_lin = (const float*)d_in[3];
    const float* w1_o1  = (const float*)d_in[4];
    const float* b1_o1  = (const float*)d_in[5];
    const float* w1_o2  = (const float*)d_in[6];
    const float* b1_o2  = (const float*)d_in[7];
    const float* w2_lin = (const float*)d_in[8];
    const float* b2_lin = (const float*)d_in[9];
    const float* w2_o1  = (const float*)d_in[10];
    const float* b2_o1  = (const float*)d_in[11];
    const float* w2_o2  = (const float*)d_in[12];
    const float* b2_o2  = (const float*)d_in[13];

    const int n = in_sizes[0] / FIN;   // 100000
    const int e = in_sizes[1] / 2;     // 1000000
    const int* src = ei;
    const int* dst = ei + e;

    // Float scratch in d_ws:
    float* ws0 = (float*)d_ws;
    float* ws1 = ws0 + (size_t)n * HD;
    float* h1   = ws0;
    float* agg1 = ws1;
    float* h2   = ws0;   // postlin writes h2 over h1 (h1 dead after gather1)
    float* agg2 = ws1;   // gather2 writes over agg1 (dead after postlin)
    float* outp = (float*)d_out;

    // CSR arrays live in d_out (16 MB; consumed before the final post kernel).
    int* eidx     = (int*)d_out;
    int* deg      = eidx + e;
    int* rowptr   = deg + n;
    int* chunkSum = rowptr + n;

    const int nchunks = (n + 1023) / 1024;        // 98 (<=128)
    const int egrid   = (e + 255) / 256;
    const int ngrid   = (n + 255) / 256;
    const int ggrid   = (n + 3) / 4;

    // ---- CSR build (reused by both layers) ----
    hipMemsetAsync(deg, 0, (size_t)n * sizeof(int), stream);
    hist_kernel<<<egrid, 256, 0, stream>>>(dst, deg, e);
    chunksum_kernel<<<nchunks, 256, 0, stream>>>(deg, chunkSum, n);
    scanchunks_kernel<<<1, 128, 0, stream>>>(chunkSum, nchunks);
    scanwithin_kernel<<<nchunks, 256, 0, stream>>>(deg, chunkSum, rowptr, n);
    fill_kernel<<<egrid, 256, 0, stream>>>(src, dst, rowptr, eidx, e);

    // ---- conv1 + conv2.lin ----
    lin_kernel<FIN, HD><<<ngrid, 256, 0, stream>>>(x, w1_lin, b1_lin, h1, n);
    gather_kernel<HD><<<ggrid, 256, 0, stream>>>(rowptr, deg, eidx, h1, agg1, n);
    postlin_kernel<HD, CD><<<ngrid, 256, 0, stream>>>(
        agg1, w1_o1, b1_o1, w1_o2, b1_o2, w2_lin, b2_lin, h2, n);

    // ---- conv2 ----
    gather_kernel<CD><<<ggrid, 256, 0, stream>>>(rowptr, deg, eidx, h2, agg2, n);
    post_kernel<CD, false><<<ngrid, 256, 0, stream>>>(agg2, w2_o1, b2_o1, w2_o2, b2_o2, outp, n);
}

// Round 4
// 698.527 us; speedup vs baseline: 2.8197x; 1.0651x over previous
//
#include <hip/hip_runtime.h>

static constexpr int FIN = 128;
static constexpr int HD  = 64;
static constexpr int CD  = 40;

// ---------------------------------------------------------------------------
// Dense: out[n][o] = bias[o] + sum_k in[n][k] * W[o][k].  One lane per node.
// acc[] fully statically indexed -> registers; weights wave-uniform -> s_load.
// ---------------------------------------------------------------------------
template<int K, int O>
__global__ __launch_bounds__(256, 3)
void lin_kernel(const float* __restrict__ in, const float* __restrict__ W,
                const float* __restrict__ bias, float* __restrict__ out, int n)
{
    int node = blockIdx.x * 256 + threadIdx.x;
    if (node >= n) return;
    float acc[O];
#pragma unroll
    for (int o = 0; o < O; ++o) acc[o] = bias[o];
    const float* row = in + (size_t)node * K;
#pragma unroll 1
    for (int k = 0; k < K; k += 4) {
        float4 v = *reinterpret_cast<const float4*>(row + k);
#pragma unroll
        for (int o = 0; o < O; ++o) {
            const float* wr = W + o * K + k;   // uniform address -> scalar load
            acc[o] = fmaf(v.x, wr[0], acc[o]);
            acc[o] = fmaf(v.y, wr[1], acc[o]);
            acc[o] = fmaf(v.z, wr[2], acc[o]);
            acc[o] = fmaf(v.w, wr[3], acc[o]);
        }
    }
    float* orow = out + (size_t)node * O;
#pragma unroll
    for (int o = 0; o < O; o += 4)
        *reinterpret_cast<float4*>(orow + o) =
            make_float4(acc[o], acc[o + 1], acc[o + 2], acc[o + 3]);
}

// ---------------------------------------------------------------------------
// Fused conv1-tail + conv2-lin:
//   u = relu(W1 relu(agg) + b1); v = relu(W2 u + b2); out = W3 v + b3
// Outer-product form: k-loop rolled (dynamic float4 read of the k-vector,
// which may live in scratch — 1 load per 64 FMAs), o-loop fully unrolled so
// acc[] stays in registers.  NO bulk spills.
// ---------------------------------------------------------------------------
template<int D, int O>
__global__ __launch_bounds__(256, 3)
void postlin_kernel(const float* __restrict__ agg,
                    const float* __restrict__ W1, const float* __restrict__ b1,
                    const float* __restrict__ W2, const float* __restrict__ b2,
                    const float* __restrict__ W3, const float* __restrict__ b3,
                    float* __restrict__ out, int n)
{
    int node = blockIdx.x * 256 + threadIdx.x;
    if (node >= n) return;
    const float* row = agg + (size_t)node * D;

    float acc[D];
    float u[D];          // scratch-resident k-vector between matmuls

    // phase 1: acc = W1 * relu(row) + b1   (relu applied to chunk on the fly)
#pragma unroll
    for (int o = 0; o < D; ++o) acc[o] = b1[o];
#pragma unroll 1
    for (int k = 0; k < D; k += 4) {
        float4 v = *reinterpret_cast<const float4*>(row + k);
        v.x = fmaxf(v.x, 0.f); v.y = fmaxf(v.y, 0.f);
        v.z = fmaxf(v.z, 0.f); v.w = fmaxf(v.w, 0.f);
#pragma unroll
        for (int o = 0; o < D; ++o) {
            const float* wr = W1 + o * D + k;
            acc[o] = fmaf(v.x, wr[0], acc[o]);
            acc[o] = fmaf(v.y, wr[1], acc[o]);
            acc[o] = fmaf(v.z, wr[2], acc[o]);
            acc[o] = fmaf(v.w, wr[3], acc[o]);
        }
    }
#pragma unroll
    for (int o = 0; o < D; ++o) u[o] = fmaxf(acc[o], 0.f);

    // phase 2: acc = W2 * u + b2
#pragma unroll
    for (int o = 0; o < D; ++o) acc[o] = b2[o];
#pragma unroll 1
    for (int k = 0; k < D; k += 4) {
        float4 v = *reinterpret_cast<const float4*>(&u[k]);  // dynamic base
#pragma unroll
        for (int o = 0; o < D; ++o) {
            const float* wr = W2 + o * D + k;
            acc[o] = fmaf(v.x, wr[0], acc[o]);
            acc[o] = fmaf(v.y, wr[1], acc[o]);
            acc[o] = fmaf(v.z, wr[2], acc[o]);
            acc[o] = fmaf(v.w, wr[3], acc[o]);
        }
    }
#pragma unroll
    for (int o = 0; o < D; ++o) u[o] = fmaxf(acc[o], 0.f);

    // phase 3: out = W3 * u + b3
    float acc2[O];
#pragma unroll
    for (int o = 0; o < O; ++o) acc2[o] = b3[o];
#pragma unroll 1
    for (int k = 0; k < D; k += 4) {
        float4 v = *reinterpret_cast<const float4*>(&u[k]);
#pragma unroll
        for (int o = 0; o < O; ++o) {
            const float* wr = W3 + o * D + k;
            acc2[o] = fmaf(v.x, wr[0], acc2[o]);
            acc2[o] = fmaf(v.y, wr[1], acc2[o]);
            acc2[o] = fmaf(v.z, wr[2], acc2[o]);
            acc2[o] = fmaf(v.w, wr[3], acc2[o]);
        }
    }
    float* orow = out + (size_t)node * O;
#pragma unroll
    for (int o = 0; o < O; o += 4)
        *reinterpret_cast<float4*>(orow + o) =
            make_float4(acc2[o], acc2[o + 1], acc2[o + 2], acc2[o + 3]);
}

// ---------------------------------------------------------------------------
// Conv tail: u = relu(W1 relu(agg) + b1); out = W2 u + b2  (no final relu)
// Same outer-product structure.
// ---------------------------------------------------------------------------
template<int D, bool FINAL_RELU>
__global__ __launch_bounds__(256, 3)
void post_kernel(const float* __restrict__ agg,
                 const float* __restrict__ W1, const float* __restrict__ b1,
                 const float* __restrict__ W2, const float* __restrict__ b2,
                 float* __restrict__ out, int n)
{
    int node = blockIdx.x * 256 + threadIdx.x;
    if (node >= n) return;
    const float* row = agg + (size_t)node * D;

    float acc[D];
    float u[D];

#pragma unroll
    for (int o = 0; o < D; ++o) acc[o] = b1[o];
#pragma unroll 1
    for (int k = 0; k < D; k += 4) {
        float4 v = *reinterpret_cast<const float4*>(row + k);
        v.x = fmaxf(v.x, 0.f); v.y = fmaxf(v.y, 0.f);
        v.z = fmaxf(v.z, 0.f); v.w = fmaxf(v.w, 0.f);
#pragma unroll
        for (int o = 0; o < D; ++o) {
            const float* wr = W1 + o * D + k;
            acc[o] = fmaf(v.x, wr[0], acc[o]);
            acc[o] = fmaf(v.y, wr[1], acc[o]);
            acc[o] = fmaf(v.z, wr[2], acc[o]);
            acc[o] = fmaf(v.w, wr[3], acc[o]);
        }
    }
#pragma unroll
    for (int o = 0; o < D; ++o) u[o] = fmaxf(acc[o], 0.f);

#pragma unroll
    for (int o = 0; o < D; ++o) acc[o] = b2[o];
#pragma unroll 1
    for (int k = 0; k < D; k += 4) {
        float4 v = *reinterpret_cast<const float4*>(&u[k]);
#pragma unroll
        for (int o = 0; o < D; ++o) {
            const float* wr = W2 + o * D + k;
            acc[o] = fmaf(v.x, wr[0], acc[o]);
            acc[o] = fmaf(v.y, wr[1], acc[o]);
            acc[o] = fmaf(v.z, wr[2], acc[o]);
            acc[o] = fmaf(v.w, wr[3], acc[o]);
        }
    }
    float* orow = out + (size_t)node * D;
#pragma unroll
    for (int o = 0; o < D; o += 4) {
        float4 r;
        r.x = FINAL_RELU ? fmaxf(acc[o], 0.f)     : acc[o];
        r.y = FINAL_RELU ? fmaxf(acc[o + 1], 0.f) : acc[o + 1];
        r.z = FINAL_RELU ? fmaxf(acc[o + 2], 0.f) : acc[o + 2];
        r.w = FINAL_RELU ? fmaxf(acc[o + 3], 0.f) : acc[o + 3];
        *reinterpret_cast<float4*>(orow + o) = r;
    }
}

// ---------------------------------------------------------------------------
// CSR build.
// ---------------------------------------------------------------------------
__global__ __launch_bounds__(256)
void hist_kernel(const int* __restrict__ dst, int* __restrict__ deg, int e)
{
    int i = blockIdx.x * 256 + threadIdx.x;
    if (i < e) atomicAdd(&deg[dst[i]], 1);
}

__global__ __launch_bounds__(256)
void chunksum_kernel(const int* __restrict__ deg, int* __restrict__ chunkSum, int n)
{
    __shared__ int s[256];
    int t = threadIdx.x;
    int base = blockIdx.x * 1024 + t * 4;
    int v = 0;
#pragma unroll
    for (int i = 0; i < 4; ++i) if (base + i < n) v += deg[base + i];
    s[t] = v; __syncthreads();
    for (int off = 128; off > 0; off >>= 1) {
        if (t < off) s[t] += s[t + off];
        __syncthreads();
    }
    if (t == 0) chunkSum[blockIdx.x] = s[0];
}

__global__ __launch_bounds__(128)
void scanchunks_kernel(int* __restrict__ chunkSum, int nchunks)
{
    __shared__ int s[128];
    int t = threadIdx.x;
    int v = (t < nchunks) ? chunkSum[t] : 0;
    s[t] = v; __syncthreads();
    for (int off = 1; off < 128; off <<= 1) {
        int a = (t >= off) ? s[t - off] : 0;
        __syncthreads();
        s[t] += a;
        __syncthreads();
    }
    if (t < nchunks) chunkSum[t] = s[t] - v;   // exclusive
}

__global__ __launch_bounds__(256)
void scanwithin_kernel(const int* __restrict__ deg, const int* __restrict__ chunkOff,
                       int* __restrict__ rowptr, int n)
{
    __shared__ int s[256];
    int t = threadIdx.x;
    int base = blockIdx.x * 1024 + t * 4;
    int v[4]; int sum = 0;
#pragma unroll
    for (int i = 0; i < 4; ++i) { v[i] = (base + i < n) ? deg[base + i] : 0; sum += v[i]; }
    s[t] = sum; __syncthreads();
    for (int off = 1; off < 256; off <<= 1) {
        int a = (t >= off) ? s[t - off] : 0;
        __syncthreads();
        s[t] += a;
        __syncthreads();
    }
    int p = s[t] - sum + chunkOff[blockIdx.x];
#pragma unroll
    for (int i = 0; i < 4; ++i) {
        if (base + i < n) rowptr[base + i] = p;
        p += v[i];
    }
}

__global__ __launch_bounds__(256)
void fill_kernel(const int* __restrict__ src, const int* __restrict__ dst,
                 int* __restrict__ rowptr, int* __restrict__ eidx, int e)
{
    int i = blockIdx.x * 256 + threadIdx.x;
    if (i >= e) return;
    int pos = atomicAdd(&rowptr[dst[i]], 1);
    eidx[pos] = src[i];
}

// ---------------------------------------------------------------------------
// Gather: agg[d][c] = h[d][c] + sum_{e: dst=d} h[src_e][c].
// One wave per node, lane = channel.
// ---------------------------------------------------------------------------
template<int D>
__global__ __launch_bounds__(256)
void gather_kernel(const int* __restrict__ rowptr_end, const int* __restrict__ deg,
                   const int* __restrict__ eidx, const float* __restrict__ h,
                   float* __restrict__ agg, int n)
{
    int wave = threadIdx.x >> 6;
    int lane = threadIdx.x & 63;
    int node = blockIdx.x * 4 + wave;
    if (node >= n) return;
    bool act = (lane < D);
    float acc = act ? h[(size_t)node * D + lane] : 0.f;
    int end = rowptr_end[node];
    int start = end - deg[node];
    for (int base = start; base < end; base += 64) {
        int m = min(64, end - base);
        int sv = (lane < m) ? eidx[base + lane] : 0;
        for (int j = 0; j < m; ++j) {
            int s = __shfl(sv, j, 64);
            if (act) acc += h[(size_t)s * D + lane];
        }
    }
    if (act) agg[(size_t)node * D + lane] = acc;
}

extern "C" void kernel_launch(void* const* d_in, const int* in_sizes, int n_in,
                              void* d_out, int out_size, void* d_ws, size_t ws_size,
                              hipStream_t stream)
{
    const float* x      = (const float*)d_in[0];
    const int*   ei     = (const int*)d_in[1];
    const float* w1_lin = (const float*)d_in[2];
    const float* b1_lin = (const float*)d_in[3];
    const float* w1_o1  = (const float*)d_in[4];
    const float* b1_o1  = (const float*)d_in[5];
    const float* w1_o2  = (const float*)d_in[6];
    const float* b1_o2  = (const float*)d_in[7];
    const float* w2_lin = (const float*)d_in[8];
    const float* b2_lin = (const float*)d_in[9];
    const float* w2_o1  = (const float*)d_in[10];
    const float* b2_o1  = (const float*)d_in[11];
    const float* w2_o2  = (const float*)d_in[12];
    const float* b2_o2  = (const float*)d_in[13];

    const int n = in_sizes[0] / FIN;   // 100000
    const int e = in_sizes[1] / 2;     // 1000000
    const int* src = ei;
    const int* dst = ei + e;

    // Float scratch in d_ws:
    float* ws0 = (float*)d_ws;
    float* ws1 = ws0 + (size_t)n * HD;
    float* h1   = ws0;
    float* agg1 = ws1;
    float* h2   = ws0;   // postlin writes h2 over h1 (h1 dead after gather1)
    float* agg2 = ws1;   // gather2 writes over agg1 (dead after postlin)
    float* outp = (float*)d_out;

    // CSR arrays live in d_out (16 MB; consumed before the final post kernel).
    int* eidx     = (int*)d_out;
    int* deg      = eidx + e;
    int* rowptr   = deg + n;
    int* chunkSum = rowptr + n;

    const int nchunks = (n + 1023) / 1024;        // 98 (<=128)
    const int egrid   = (e + 255) / 256;
    const int ngrid   = (n + 255) / 256;
    const int ggrid   = (n + 3) / 4;

    // ---- CSR build (reused by both layers) ----
    hipMemsetAsync(deg, 0, (size_t)n * sizeof(int), stream);
    hist_kernel<<<egrid, 256, 0, stream>>>(dst, deg, e);
    chunksum_kernel<<<nchunks, 256, 0, stream>>>(deg, chunkSum, n);
    scanchunks_kernel<<<1, 128, 0, stream>>>(chunkSum, nchunks);
    scanwithin_kernel<<<nchunks, 256, 0, stream>>>(deg, chunkSum, rowptr, n);
    fill_kernel<<<egrid, 256, 0, stream>>>(src, dst, rowptr, eidx, e);

    // ---- conv1 + conv2.lin ----
    lin_kernel<FIN, HD><<<ngrid, 256, 0, stream>>>(x, w1_lin, b1_lin, h1, n);
    gather_kernel<HD><<<ggrid, 256, 0, stream>>>(rowptr, deg, eidx, h1, agg1, n);
    postlin_kernel<HD, CD><<<ngrid, 256, 0, stream>>>(
        agg1, w1_o1, b1_o1, w1_o2, b1_o2, w2_lin, b2_lin, h2, n);

    // ---- conv2 ----
    gather_kernel<CD><<<ggrid, 256, 0, stream>>>(rowptr, deg, eidx, h2, agg2, n);
    post_kernel<CD, false><<<ngrid, 256, 0, stream>>>(agg2, w2_o1, b2_o1, w2_o2, b2_o2, outp, n);
}